// Round 1
// baseline (143.285 us; speedup 1.0000x reference)
//
#include <hip/hip_runtime.h>

typedef _Float16 half_t;
typedef _Float16 half8 __attribute__((ext_vector_type(8)));
typedef _Float16 half4 __attribute__((ext_vector_type(4)));
typedef _Float16 half2v __attribute__((ext_vector_type(2)));
typedef float f32x4 __attribute__((ext_vector_type(4)));
typedef float f32x16 __attribute__((ext_vector_type(16)));
typedef unsigned int uint4v __attribute__((ext_vector_type(4)));

#define MFMA_S(a, b, c) __builtin_amdgcn_mfma_f32_32x32x16_f16((a), (b), (c), 0, 0, 0)

static constexpr int kM  = 512;
static constexpr int kD  = 64;
static constexpr int kKL = 2560;
static constexpr int kL  = 2048;
// ws (halves): q_scaled | K [bh][k][d] | Vc chunked [bh][80][64][32] | peT [l][d] | zm (f32)
static constexpr int WS_QS  = 0;                    // 1,048,576
static constexpr int WS_KB  = 1048576;              // 5,242,880
static constexpr int WS_VC  = WS_KB + 5242880;      // 5,242,880
static constexpr int WS_PET = WS_VC + 5242880;      // 131,072
static constexpr int WS_Z   = WS_PET + 131072;      // zeroed region (zm uses 64KB)

// ---------- K1: q/k convert + V chunked-transpose + pe transpose + zero out/z ----------
__global__ __launch_bounds__(256) void prep_kernel(const float* __restrict__ q,
    const float* __restrict__ k, const float* __restrict__ v,
    const float* __restrict__ pe, half_t* __restrict__ ws, float* __restrict__ out) {
  __shared__ float ls[64 * 72];
  const int b = blockIdx.x, t = threadIdx.x;
  if (b < 3072) {
    const int i = b * 256 + t;
    const float QS = 0.125f * 1.4426950408889634f;  // 1/sqrt(64) * log2(e)
    const float* src; half_t* dst; float sc;
    if (i < 131072) { src = q + (size_t)i * 8; dst = ws + WS_QS + (size_t)i * 8; sc = QS; }
    else { const int j = i - 131072; src = k + (size_t)j * 8; dst = ws + WS_KB + (size_t)j * 8; sc = 1.0f; }
    const float4 a = ((const float4*)src)[0];
    const float4 bb = ((const float4*)src)[1];
    half_t tt[8];
    tt[0] = (half_t)(a.x * sc);  tt[1] = (half_t)(a.y * sc);
    tt[2] = (half_t)(a.z * sc);  tt[3] = (half_t)(a.w * sc);
    tt[4] = (half_t)(bb.x * sc); tt[5] = (half_t)(bb.y * sc);
    tt[6] = (half_t)(bb.z * sc); tt[7] = (half_t)(bb.w * sc);
    *(int4*)dst = *(int4*)tt;
    return;
  }
  if (b >= 4384) {
    if (b < 4640) {                       // zero d_out
      float4* o = (float4*)out;
      const int base = (b - 4384) * 1024 + t;
#pragma unroll
      for (int u = 0; u < 4; ++u) o[base + u * 256] = float4{0, 0, 0, 0};
    } else {                              // zero z region
      float4* z = (float4*)((float*)(ws + WS_Z));
      const int base = (b - 4640) * 1024 + t;
#pragma unroll
      for (int u = 0; u < 4; ++u) z[base + u * 256] = float4{0, 0, 0, 0};
    }
    return;
  }
  const bool isV = (b < 4352);
  int bh = 0, kt = 0, b3 = 0;
  const float* src; int sstride;
  if (isV) {
    const int b2 = b - 3072;
    bh = b2 / 40; kt = b2 % 40;
    src = v + (size_t)(bh * 2560 + kt * 64) * 64; sstride = 64;
  } else {
    b3 = b - 4352;
    src = pe + (size_t)b3 * 64; sstride = 2048;
  }
  const int rr = t >> 4, cq = (t & 15) * 4;
#pragma unroll
  for (int p = 0; p < 4; ++p) {
    const float4 x = *(const float4*)(src + (size_t)(p * 16 + rr) * sstride + cq);
    *(float4*)(ls + (p * 16 + rr) * 72 + cq) = x;
  }
  __syncthreads();
  const int oc = t >> 2, ch = t & 3;
  half_t tmp[16];
#pragma unroll
  for (int i2 = 0; i2 < 16; ++i2) tmp[i2] = (half_t)ls[(ch * 16 + i2) * 72 + oc];
  half_t* o;
  if (isV) {
    o = ws + WS_VC + (size_t)bh * 163840 + ((kt << 1) + (ch >> 1)) * 2048 + oc * 32 + ((ch & 1) << 4);
  } else {
    o = ws + WS_PET + ((size_t)b3 * 64 + oc) * 64 + ch * 16;
  }
  ((int4*)o)[0] = ((int4*)tmp)[0];
  ((int4*)o)[1] = ((int4*)tmp)[1];
}

// ---------- K2: 32x32-MFMA split-K attention ----------
// grid 1024 = 32bh x 4 m-blocks(128 rows) x 8 K-splits (9/8 of 68 chunks);
// block 256 (4 waves); wave w computes a 32-row x 32-key tile per step via
// v_mfma_f32_32x32x16_f16: S^T = K.Q^T (4 MFMA), PV O^T = V^T.P (4 MFMA),
// PE bias (4 MFMA/step). R15: P C->B refragmentation now fully in-register via
// v_cvt_f16 (RNE, bit-identical to R14) + v_permlane32_swap_b32 (half-wave
// exchange is the only cross-lane movement needed); removes 4 ds_write_b64 +
// 2 ds_read_b128 + lgkm wait from the per-step chain and frees the 10 KB P
// strip. LDS 36,864 B -> 4 blocks/CU; split-K 8 -> grid 1024 = 4 blocks/CU
// (was grid-limited at 2). Attacks the measured latency bound
// (MfmaUtil 10% / VALUBusy 32% / Occupancy 17.7%).
// Layouts (32x32x16): A[m=lane&31][k=8*(lane>>5)+j]; B[k=8*(lane>>5)+j][n=lane&31];
// C: col=lane&31, row=(reg&3)+8*(reg>>2)+4*(lane>>5).
// Em strip (ring 64, u=(l+m)&63): scalar b16 writes (wrap-safe), b64 reads
// (no-wrap: read base = B+8q+4h is a multiple of 4).
// LDS: K 2x4608 | Vc 2x5120 | Em 4x4352 = 36,864 B.
__global__ __launch_bounds__(256, 4) void attn_kernel(
    const half_t* __restrict__ ws, const float* __restrict__ cvp,
    float* __restrict__ out, float* __restrict__ zmA) {

  __shared__ __align__(16) char smem[36864];
  half_t* lsh = (half_t*)smem;

  const int tid  = threadIdx.x;
  const int lane = tid & 63;
  const int w    = tid >> 6;                    // wave 0..3
  const int c32  = lane & 31;                   // MFMA col (query m / key / d)
  const int h    = lane >> 5;                   // half-wave

  const int id = blockIdx.x;                    // 1024
  const int bh = ((id & 7) << 2) | (id >> 8);   // XCD-aware: bh's 32 (mb,sp) blocks share an XCD
  const int mid = (id >> 3) & 31;
  const int mb = mid & 3, sp = mid >> 2;
  const int m0 = mb << 7;                       // 128 rows per block
  const int g0 = (sp << 3) + (sp < 4 ? sp : 4); // chunk ranges: 9,9,9,9,8,8,8,8
  const int cnt = (sp < 4) ? 9 : 8;

  const float cvl = cvp[bh & 7] * 2048.0f - 2047.0f;  // mask = clamp((l+cvl)/64+1,0,1)
  const float cvO = cvl * 0.015625f + 1.0f;

  const half_t* kb  = ws + WS_KB + (size_t)bh * (kKL * kD);
  const half_t* vcb = ws + WS_VC + (size_t)bh * (kKL * kD);
  const half_t* pet = ws + WS_PET;

  // Q B-frags: B[k=d=16t+8h+j][n=m=c32], t=0..3
  const half_t* qrow = ws + WS_QS + (size_t)(bh * kM + m0 + 32 * w + c32) * kD;
  half8 bq[4];
#pragma unroll
  for (int t = 0; t < 4; ++t) bq[t] = *(const half8*)(qrow + t * 16 + h * 8);

  // LDS (halves): K ring 2x2304 @0 | Vc ring 2x2560 @4608 | Em 4x2176 @9728
  half_t* stf = lsh + 9728 + w * 2176 + c32 * 68;     // Em strip row m=c32

  int4 stgK, stgV;
  auto issueKV = [&](int gg) {
    const int r = tid >> 3, seg = tid & 7;
    const int krow = m0 + (gg << 5) + r;               // max 2559
    stgK = *(const int4*)(kb + (size_t)krow * kD + seg * 8);
    const int vch = (m0 >> 5) + gg;                    // max 79
    stgV = *(const int4*)(vcb + (size_t)vch * 2048 + tid * 8);
  };
  auto commitKV = [&](int gg) {
    const int sK = (gg & 1) * 2304;
    const int sV = 4608 + (gg & 1) * 2560;
    const int r = tid >> 3, seg = tid & 7;
    *(int4*)(lsh + sK + r * 72 + seg * 8) = stgK;
    const int d = tid >> 2, ks = (tid & 3) * 8;
    *(int4*)(lsh + sV + d * 40 + ks) = stgV;
  };

  // PE bias window [wb, wb+32): C[row=l-wb][col=m], A from global peT (divergent
  // but off critical path)
  auto peWindow = [&](int wb) -> f32x16 {
    int l = wb + c32; l = l < 0 ? 0 : (l > kL - 1 ? kL - 1 : l);
    const half_t* pp = pet + (size_t)l * kD;
    f32x16 a = {};
#pragma unroll
    for (int t = 0; t < 4; ++t) {
      const half8 p = *(const half8*)(pp + t * 16 + h * 8);
      a = MFMA_S(p, bq[t], a);
    }
    return a;
  };
  auto stripWrite = [&](int wb, const f32x16& a) {
    const int allone  = (wb >= 0) && (wb + 31 <= kL - 1) && (wb + cvl >= 0.0f);
    const int allzero = (wb > kL - 1) || (wb + 31 < 0) || ((float)(wb + 31) + cvl <= -64.0f);
#pragma unroll
    for (int reg = 0; reg < 16; ++reg) {
      const int lr = (reg & 3) + 8 * (reg >> 2) + 4 * h;
      const int l  = wb + lr;
      const float bt = a[reg] * 0.6931472f;
      float e = __builtin_fmaf(bt, 0.16666667f, 0.5f);   // exp2(bias) poly
      e = __builtin_fmaf(e, bt, 1.0f);
      e = __builtin_fmaf(e, bt, 1.0f);
      float em;
      if (allzero) em = 0.0f;
      else if (allone) em = e;
      else {
        const float mk = fminf(fmaxf((float)l * 0.015625f + cvO, 0.0f), 1.0f);
        em = ((unsigned)l < (unsigned)kL) ? e * mk : 0.0f;
      }
      stf[(l + c32) & 63] = (half_t)em;
    }
  };

  // ---- prime: K/V chunk g0 + Em windows [B0-32, B0) and [B0, B0+32) ----
  issueKV(g0);
  const int B0 = (g0 << 5) - 32 * w;
  stripWrite(B0 - 32, peWindow(B0 - 32));
  stripWrite(B0,      peWindow(B0));
  commitKV(g0);
  __syncthreads();

  float zmc = 0.0f;
  f32x16 o0 = {}, o1 = {};                      // O^T d in [0,32) / [32,64)

  for (int t = 0; t < cnt; ++t) {
    const int g = g0 + t;
    const bool more = (t + 1 < cnt);
    if (more) issueKV(g + 1);

    const int sK = (g & 1) * 2304;
    const int sV = 4608 + (g & 1) * 2560;
    const int B = (g << 5) - 32 * w;            // l of key0 vs m=c32=0

    // K A-frags: A[m=key=c32][k=16t+8h+j]
    half8 ak[4];
#pragma unroll
    for (int kt = 0; kt < 4; ++kt)
      ak[kt] = *(const half8*)(lsh + sK + c32 * 72 + kt * 16 + h * 8);

    // Em quads (written at previous step): u = B + 8q + 4h (+r), mult of 4 -> no wrap
    half4 emq[4];
#pragma unroll
    for (int q = 0; q < 4; ++q)
      emq[q] = *(const half4*)(stf + ((B + 8 * q + 4 * h) & 63));

    // V^T A-frags: A[m=d-32dh=c32][k=16kt+8h+j]
    half8 av[2][2];
#pragma unroll
    for (int dh = 0; dh < 2; ++dh)
#pragma unroll
      for (int kt = 0; kt < 2; ++kt)
        av[dh][kt] = *(const half8*)(lsh + sV + (32 * dh + c32) * 40 + kt * 16 + h * 8);

    // ---- S^T = K.Q^T ----
    f32x16 s = {};
#pragma unroll
    for (int kt = 0; kt < 4; ++kt) s = MFMA_S(ak[kt], bq[kt], s);

    // ---- softmax: pm = exp2(s) * Em, f16 RNE convert (bit-identical to LDS path) ----
    float pm[16];
#pragma unroll
    for (int reg = 0; reg < 16; ++reg) {
      pm[reg] = __builtin_amdgcn_exp2f(s[reg]) * (float)emq[reg >> 2][reg & 3];
      zmc += pm[reg];
    }
    // pack pairs: W[q] covers keys {2q,2q+1} of this half's C-key-set
    unsigned Wp[8];
#pragma unroll
    for (int q = 0; q < 8; ++q) {
      const half2v hp = { (half_t)pm[2 * q], (half_t)pm[2 * q + 1] };
      Wp[q] = __builtin_bit_cast(unsigned, hp);
    }
    // C->B refragmentation in-register: half-wave exchange.
    // swap(W0,W2): r.x = {h0:keys(0,1), h1:keys(8,9)} = pb0 word0;
    //              r.y = {h0:keys(4,5), h1:keys(12,13)} = pb0 word2.
    const auto r0 = __builtin_amdgcn_permlane32_swap(Wp[0], Wp[2], false, false);
    const auto r1 = __builtin_amdgcn_permlane32_swap(Wp[1], Wp[3], false, false);
    const auto r2 = __builtin_amdgcn_permlane32_swap(Wp[4], Wp[6], false, false);
    const auto r3 = __builtin_amdgcn_permlane32_swap(Wp[5], Wp[7], false, false);
    const uint4v u0 = { (unsigned)r0[0], (unsigned)r1[0], (unsigned)r0[1], (unsigned)r1[1] };
    const uint4v u1 = { (unsigned)r2[0], (unsigned)r3[0], (unsigned)r2[1], (unsigned)r3[1] };
    const half8 pb0 = __builtin_bit_cast(half8, u0);   // B[k=8h+j][m], keys 0..15
    const half8 pb1 = __builtin_bit_cast(half8, u1);   // keys 16..31

    // ---- PV: O^T[d][m] += V^T.P ----
    o0 = MFMA_S(av[0][0], pb0, o0);
    o0 = MFMA_S(av[0][1], pb1, o0);
    o1 = MFMA_S(av[1][0], pb0, o1);
    o1 = MFMA_S(av[1][1], pb1, o1);

    // ---- Em window for t+1 (after reads): [B+32, B+64) ----
    if (more) {
      stripWrite(B + 32, peWindow(B + 32));
      commitKV(g + 1);
    }
    __syncthreads();
  }

  // ---- epilogue ----
  __syncthreads();                              // safe to overlay LDS
  float* Ow = (float*)smem + (size_t)w * 2176;  // [32 m][stride 68] f32
#pragma unroll
  for (int q = 0; q < 4; ++q) {
    *(f32x4*)(Ow + c32 * 68 + 0  + 8 * q + 4 * h) =
        f32x4{o0[q * 4], o0[q * 4 + 1], o0[q * 4 + 2], o0[q * 4 + 3]};
    *(f32x4*)(Ow + c32 * 68 + 32 + 8 * q + 4 * h) =
        f32x4{o1[q * 4], o1[q * 4 + 1], o1[q * 4 + 2], o1[q * 4 + 3]};
  }
  zmc += __shfl_xor(zmc, 32);
  if (lane < 32) {
    const int row = bh * kM + m0 + 32 * w + c32;
    atomicAdd(&zmA[row], zmc);
  }
  const int rowbase = bh * kM + m0 + 32 * w;
  for (int rr = 0; rr < 32; ++rr)
    atomicAdd(out + (size_t)(rowbase + rr) * kD + lane, Ow[rr * 68 + lane]);
}

// ---------- K3: normalize ----------
__global__ __launch_bounds__(256) void norm_kernel(const float* __restrict__ zmA,
    float* __restrict__ out) {
  const int i = blockIdx.x * 256 + threadIdx.x;   // 262,144
  const int row = i >> 4, d4 = (i & 15) << 2;
  const float inv = 1.0f / (zmA[row] + 1e-20f);
  float4* p = (float4*)(out + (size_t)row * 64 + d4);
  float4 v = *p;
  v.x *= inv; v.y *= inv; v.z *= inv; v.w *= inv;
  *p = v;
}

extern "C" void kernel_launch(void* const* d_in, const int* in_sizes, int n_in,
                              void* d_out, int out_size, void* d_ws, size_t ws_size,
                              hipStream_t stream) {
  (void)in_sizes; (void)n_in; (void)out_size; (void)ws_size;
  const float* q  = (const float*)d_in[0];
  const float* k  = (const float*)d_in[1];
  const float* v  = (const float*)d_in[2];
  const float* pe = (const float*)d_in[3];
  const float* cv = (const float*)d_in[4];
  half_t* ws = (half_t*)d_ws;   // needs ~23.6 MB
  float* out = (float*)d_out;
  float* zmA = (float*)(ws + WS_Z);

  prep_kernel<<<4648, 256, 0, stream>>>(q, k, v, pe, ws, out);
  attn_kernel<<<1024, 256, 0, stream>>>(ws, cv, out, zmA);
  norm_kernel<<<1024, 256, 0, stream>>>(zmA, out);
}

// Round 2
// 134.503 us; speedup vs baseline: 1.0653x; 1.0653x over previous
//
#include <hip/hip_runtime.h>
#include <math.h>

typedef _Float16 half_t;
typedef _Float16 half8 __attribute__((ext_vector_type(8)));
typedef _Float16 half4 __attribute__((ext_vector_type(4)));
typedef _Float16 half2v __attribute__((ext_vector_type(2)));
typedef float f32x4 __attribute__((ext_vector_type(4)));
typedef float f32x16 __attribute__((ext_vector_type(16)));
typedef unsigned int uint4v __attribute__((ext_vector_type(4)));

#define MFMA_S(a, b, c) __builtin_amdgcn_mfma_f32_32x32x16_f16((a), (b), (c), 0, 0, 0)

static constexpr int kM  = 512;
static constexpr int kD  = 64;
static constexpr int kKL = 2560;
static constexpr int kL  = 2048;
// ws (halves): q_scaled | K [bh][k][d] | Vc chunked [bh][80][64][32] | peT [l][d]
static constexpr int WS_QS  = 0;                    // 1,048,576
static constexpr int WS_KB  = 1048576;              // 5,242,880
static constexpr int WS_VC  = WS_KB + 5242880;      // 5,242,880
static constexpr int WS_PET = WS_VC + 5242880;      // 131,072
// byte offsets past the half region (11,665,408 halves = 23,330,816 B):
static constexpr size_t WS_ZP_B = 23330816;         // zp f32 [4][16384]   (256 KB)
static constexpr size_t WS_PO_B = WS_ZP_B + 262144; // po f32 [4][16384][64] (16 MB)

// ---------- K1: q/k convert + V chunked-transpose + pe transpose ----------
// (no zero-init passes anymore: out/zm are written unconditionally downstream)
__global__ __launch_bounds__(256) void prep_kernel(const float* __restrict__ q,
    const float* __restrict__ k, const float* __restrict__ v,
    const float* __restrict__ pe, half_t* __restrict__ ws) {
  __shared__ float ls[64 * 72];
  const int b = blockIdx.x, t = threadIdx.x;
  if (b < 3072) {
    const int i = b * 256 + t;
    const float QS = 0.125f * 1.4426950408889634f;  // 1/sqrt(64) * log2(e)
    const float* src; half_t* dst; float sc;
    if (i < 131072) { src = q + (size_t)i * 8; dst = ws + WS_QS + (size_t)i * 8; sc = QS; }
    else { const int j = i - 131072; src = k + (size_t)j * 8; dst = ws + WS_KB + (size_t)j * 8; sc = 1.0f; }
    const float4 a = ((const float4*)src)[0];
    const float4 bb = ((const float4*)src)[1];
    half_t tt[8];
    tt[0] = (half_t)(a.x * sc);  tt[1] = (half_t)(a.y * sc);
    tt[2] = (half_t)(a.z * sc);  tt[3] = (half_t)(a.w * sc);
    tt[4] = (half_t)(bb.x * sc); tt[5] = (half_t)(bb.y * sc);
    tt[6] = (half_t)(bb.z * sc); tt[7] = (half_t)(bb.w * sc);
    *(int4*)dst = *(int4*)tt;
    return;
  }
  const bool isV = (b < 4352);
  int bh = 0, kt = 0, b3 = 0;
  const float* src; int sstride;
  if (isV) {
    const int b2 = b - 3072;
    bh = b2 / 40; kt = b2 % 40;
    src = v + (size_t)(bh * 2560 + kt * 64) * 64; sstride = 64;
  } else {
    b3 = b - 4352;
    src = pe + (size_t)b3 * 64; sstride = 2048;
  }
  const int rr = t >> 4, cq = (t & 15) * 4;
#pragma unroll
  for (int p = 0; p < 4; ++p) {
    const float4 x = *(const float4*)(src + (size_t)(p * 16 + rr) * sstride + cq);
    *(float4*)(ls + (p * 16 + rr) * 72 + cq) = x;
  }
  __syncthreads();
  const int oc = t >> 2, ch = t & 3;
  half_t tmp[16];
#pragma unroll
  for (int i2 = 0; i2 < 16; ++i2) tmp[i2] = (half_t)ls[(ch * 16 + i2) * 72 + oc];
  half_t* o;
  if (isV) {
    o = ws + WS_VC + (size_t)bh * 163840 + ((kt << 1) + (ch >> 1)) * 2048 + oc * 32 + ((ch & 1) << 4);
  } else {
    o = ws + WS_PET + ((size_t)b3 * 64 + oc) * 64 + ch * 16;
  }
  ((int4*)o)[0] = ((int4*)tmp)[0];
  ((int4*)o)[1] = ((int4*)tmp)[1];
}

// ---------- K2: 32x32-MFMA split-K attention ----------
// grid 512 = 32bh x 4 m-blocks(128 rows) x 4 K-splits (17 chunks each);
// block 256 (4 waves); wave w: 32-row x 32-key tile per step via
// v_mfma_f32_32x32x16_f16: S^T = K.Q^T (4), PE bias (4), PV O^T = V^T.P (4).
// R16 changes vs R15 (which regressed: occupancy 2x bought nothing in the
// main loop -> per-CU-throughput-bound; atomics doubled to 36MB RMW):
//  (a) split-K back to 4; partial O / partial zm PLAIN-stored to workspace
//      (po[4][16384][64] f32, zp[4][16384] f32); norm does the 4-way reduce.
//      No global atomics, no zero-init of out/zm.
//  (b) Em strip now stores bias' = pe_bias + log2(mask) in f16 (log2 domain;
//      -inf encodes mask=0). Consumer folds it into the existing exp2:
//      pm = exp2(s + bias'). Producer's common (wave-uniform allone) case is
//      a bare f16 cvt -- removes ~80 VALU insts/wave-step (poly+mult) from
//      the serial chain (VALUBusy 33% vs MfmaUtil 10%). Boundary windows pay
//      one v_log_f32 per reg (rare). P refrag stays in-register (permlane).
// Layouts (32x32x16): A[m=lane&31][k=8*(lane>>5)+j]; B[k=8*(lane>>5)+j][n=lane&31];
// C: col=lane&31, row=(reg&3)+8*(reg>>2)+4*(lane>>5).
// Em strip (ring 64, u=(l+m)&63): scalar b16 writes (wrap-safe), b64 reads
// (no-wrap: read base = B+8q+4h is a multiple of 4).
// LDS: K 2x4608 | Vc 2x5120 | Em 4x4352 = 36,864 B.
__global__ __launch_bounds__(256, 2) void attn_kernel(
    const half_t* __restrict__ ws, const float* __restrict__ cvp,
    float* __restrict__ po, float* __restrict__ zp) {

  __shared__ __align__(16) char smem[36864];
  half_t* lsh = (half_t*)smem;

  const int tid  = threadIdx.x;
  const int lane = tid & 63;
  const int w    = tid >> 6;                    // wave 0..3
  const int c32  = lane & 31;                   // MFMA col (query m / key / d)
  const int h    = lane >> 5;                   // half-wave

  const int id = blockIdx.x;                    // 512
  const int bh = ((id & 7) << 2) | (id >> 7);   // XCD-aware
  const int mid = (id >> 3) & 15;
  const int mb = mid & 3, sp = mid >> 2;
  const int m0 = mb << 7;                       // 128 rows per block
  const int g0 = sp * 17;                       // chunks [g0, g0+17)

  const float cvl = cvp[bh & 7] * 2048.0f - 2047.0f;  // mask = clamp((l+cvl)/64+1,0,1)
  const float cvO = cvl * 0.015625f + 1.0f;

  const half_t* kb  = ws + WS_KB + (size_t)bh * (kKL * kD);
  const half_t* vcb = ws + WS_VC + (size_t)bh * (kKL * kD);
  const half_t* pet = ws + WS_PET;

  // Q B-frags: B[k=d=16t+8h+j][n=m=c32], t=0..3
  const half_t* qrow = ws + WS_QS + (size_t)(bh * kM + m0 + 32 * w + c32) * kD;
  half8 bq[4];
#pragma unroll
  for (int t = 0; t < 4; ++t) bq[t] = *(const half8*)(qrow + t * 16 + h * 8);

  // LDS (halves): K ring 2x2304 @0 | Vc ring 2x2560 @4608 | Em 4x2176 @9728
  half_t* stf = lsh + 9728 + w * 2176 + c32 * 68;     // Em strip row m=c32

  int4 stgK, stgV;
  auto issueKV = [&](int gg) {
    const int r = tid >> 3, seg = tid & 7;
    const int krow = m0 + (gg << 5) + r;               // max 2559
    stgK = *(const int4*)(kb + (size_t)krow * kD + seg * 8);
    const int vch = (m0 >> 5) + gg;                    // max 79
    stgV = *(const int4*)(vcb + (size_t)vch * 2048 + tid * 8);
  };
  auto commitKV = [&](int gg) {
    const int sK = (gg & 1) * 2304;
    const int sV = 4608 + (gg & 1) * 2560;
    const int r = tid >> 3, seg = tid & 7;
    *(int4*)(lsh + sK + r * 72 + seg * 8) = stgK;
    const int d = tid >> 2, ks = (tid & 3) * 8;
    *(int4*)(lsh + sV + d * 40 + ks) = stgV;
  };

  // PE bias window [wb, wb+32): C[row=l-wb][col=m], A from global peT (divergent
  // but off critical path)
  auto peWindow = [&](int wb) -> f32x16 {
    int l = wb + c32; l = l < 0 ? 0 : (l > kL - 1 ? kL - 1 : l);
    const half_t* pp = pet + (size_t)l * kD;
    f32x16 a = {};
#pragma unroll
    for (int t = 0; t < 4; ++t) {
      const half8 p = *(const half8*)(pp + t * 16 + h * 8);
      a = MFMA_S(p, bq[t], a);
    }
    return a;
  };
  // Store bias' = pe_bias + log2(mask) (f16, log2 domain; -inf == masked out).
  auto stripWrite = [&](int wb, const f32x16& a) {
    const int allone  = (wb >= 0) && (wb + 31 <= kL - 1) && (wb + cvl >= 0.0f);
    const int allzero = (wb > kL - 1) || (wb + 31 < 0) || ((float)(wb + 31) + cvl <= -64.0f);
#pragma unroll
    for (int reg = 0; reg < 16; ++reg) {
      const int lr = (reg & 3) + 8 * (reg >> 2) + 4 * h;
      const int l  = wb + lr;
      float bl;
      if (allzero) bl = -HUGE_VALF;
      else if (allone) bl = a[reg];
      else {
        const float mk = fminf(fmaxf((float)l * 0.015625f + cvO, 0.0f), 1.0f);
        const float lg = __builtin_amdgcn_logf(mk);   // v_log_f32: log2; log2(0) = -inf
        bl = ((unsigned)l < (unsigned)kL) ? a[reg] + lg : -HUGE_VALF;
      }
      stf[(l + c32) & 63] = (half_t)bl;
    }
  };

  // ---- prime: K/V chunk g0 + Em windows [B0-32, B0) and [B0, B0+32) ----
  issueKV(g0);
  const int B0 = (g0 << 5) - 32 * w;
  stripWrite(B0 - 32, peWindow(B0 - 32));
  stripWrite(B0,      peWindow(B0));
  commitKV(g0);
  __syncthreads();

  float zmc = 0.0f;
  f32x16 o0 = {}, o1 = {};                      // O^T d in [0,32) / [32,64)

  for (int t = 0; t < 17; ++t) {
    const int g = g0 + t;
    const bool more = (t < 16);
    if (more) issueKV(g + 1);

    const int sK = (g & 1) * 2304;
    const int sV = 4608 + (g & 1) * 2560;
    const int B = (g << 5) - 32 * w;            // l of key0 vs m=c32=0

    // K A-frags: A[m=key=c32][k=16t+8h+j]
    half8 ak[4];
#pragma unroll
    for (int kt = 0; kt < 4; ++kt)
      ak[kt] = *(const half8*)(lsh + sK + c32 * 72 + kt * 16 + h * 8);

    // bias' quads (written at previous step): u = B + 8q + 4h (+r), mult of 4 -> no wrap
    half4 emq[4];
#pragma unroll
    for (int q = 0; q < 4; ++q)
      emq[q] = *(const half4*)(stf + ((B + 8 * q + 4 * h) & 63));

    // V^T A-frags: A[m=d-32dh=c32][k=16kt+8h+j]
    half8 av[2][2];
#pragma unroll
    for (int dh = 0; dh < 2; ++dh)
#pragma unroll
      for (int kt = 0; kt < 2; ++kt)
        av[dh][kt] = *(const half8*)(lsh + sV + (32 * dh + c32) * 40 + kt * 16 + h * 8);

    // ---- S^T = K.Q^T ----
    f32x16 s = {};
#pragma unroll
    for (int kt = 0; kt < 4; ++kt) s = MFMA_S(ak[kt], bq[kt], s);

    // ---- softmax: pm = exp2(s + bias'), f16 RNE convert ----
    float pm[16];
#pragma unroll
    for (int reg = 0; reg < 16; ++reg) {
      pm[reg] = __builtin_amdgcn_exp2f(s[reg] + (float)emq[reg >> 2][reg & 3]);
      zmc += pm[reg];
    }
    // pack pairs: W[q] covers keys {2q,2q+1} of this half's C-key-set
    unsigned Wp[8];
#pragma unroll
    for (int q = 0; q < 8; ++q) {
      const half2v hp = { (half_t)pm[2 * q], (half_t)pm[2 * q + 1] };
      Wp[q] = __builtin_bit_cast(unsigned, hp);
    }
    // C->B refragmentation in-register: half-wave exchange.
    const auto r0 = __builtin_amdgcn_permlane32_swap(Wp[0], Wp[2], false, false);
    const auto r1 = __builtin_amdgcn_permlane32_swap(Wp[1], Wp[3], false, false);
    const auto r2 = __builtin_amdgcn_permlane32_swap(Wp[4], Wp[6], false, false);
    const auto r3 = __builtin_amdgcn_permlane32_swap(Wp[5], Wp[7], false, false);
    const uint4v u0 = { (unsigned)r0[0], (unsigned)r1[0], (unsigned)r0[1], (unsigned)r1[1] };
    const uint4v u1 = { (unsigned)r2[0], (unsigned)r3[0], (unsigned)r2[1], (unsigned)r3[1] };
    const half8 pb0 = __builtin_bit_cast(half8, u0);   // B[k=8h+j][m], keys 0..15
    const half8 pb1 = __builtin_bit_cast(half8, u1);   // keys 16..31

    // ---- PV: O^T[d][m] += V^T.P ----
    o0 = MFMA_S(av[0][0], pb0, o0);
    o0 = MFMA_S(av[0][1], pb1, o0);
    o1 = MFMA_S(av[1][0], pb0, o1);
    o1 = MFMA_S(av[1][1], pb1, o1);

    // ---- bias window for t+1 (after reads): [B+32, B+64) ----
    if (more) {
      stripWrite(B + 32, peWindow(B + 32));
      commitKV(g + 1);
    }
    __syncthreads();
  }

  // ---- epilogue: plain partial stores (no atomics) ----
  // loop-end barrier already fenced all waves' LDS reads; overlay is safe.
  float* Ow = (float*)smem + (size_t)w * 2176;  // [32 m][stride 68] f32, wave-local
#pragma unroll
  for (int q = 0; q < 4; ++q) {
    *(f32x4*)(Ow + c32 * 68 + 0  + 8 * q + 4 * h) =
        f32x4{o0[q * 4], o0[q * 4 + 1], o0[q * 4 + 2], o0[q * 4 + 3]};
    *(f32x4*)(Ow + c32 * 68 + 32 + 8 * q + 4 * h) =
        f32x4{o1[q * 4], o1[q * 4 + 1], o1[q * 4 + 2], o1[q * 4 + 3]};
  }
  zmc += __shfl_xor(zmc, 32);
  const int rowbase = bh * kM + m0 + 32 * w;
  if (lane < 32) zp[(size_t)sp * 16384 + rowbase + c32] = zmc;
  float* pob = po + ((size_t)sp * 16384 + rowbase) * 64;
#pragma unroll
  for (int u = 0; u < 8; ++u) {
    const int row = u * 4 + (lane >> 4);        // wave-local row 0..31
    const int d4 = (lane & 15) << 2;
    *(f32x4*)(pob + (size_t)row * 64 + d4) = *(const f32x4*)(Ow + row * 68 + d4);
  }
}

// ---------- K3: 4-way split reduce + normalize ----------
__global__ __launch_bounds__(256) void norm_kernel(const float* __restrict__ zp,
    const float* __restrict__ po, float* __restrict__ out) {
  const int i = blockIdx.x * 256 + threadIdx.x;   // 262,144
  const int row = i >> 4, d4 = (i & 15) << 2;
  const float z = zp[row] + zp[16384 + row] + zp[32768 + row] + zp[49152 + row];
  const float inv = 1.0f / (z + 1e-20f);
  f32x4 a = *(const f32x4*)(po + (size_t)row * 64 + d4);
  const f32x4 b = *(const f32x4*)(po + 1048576u + (size_t)row * 64 + d4);
  const f32x4 c = *(const f32x4*)(po + 2097152u + (size_t)row * 64 + d4);
  const f32x4 d = *(const f32x4*)(po + 3145728u + (size_t)row * 64 + d4);
  a = a + b + c + d;
  *(f32x4*)(out + (size_t)row * 64 + d4) = a * inv;
}

extern "C" void kernel_launch(void* const* d_in, const int* in_sizes, int n_in,
                              void* d_out, int out_size, void* d_ws, size_t ws_size,
                              hipStream_t stream) {
  (void)in_sizes; (void)n_in; (void)out_size; (void)ws_size;
  const float* q  = (const float*)d_in[0];
  const float* k  = (const float*)d_in[1];
  const float* v  = (const float*)d_in[2];
  const float* pe = (const float*)d_in[3];
  const float* cv = (const float*)d_in[4];
  half_t* ws = (half_t*)d_ws;   // needs ~40.4 MB
  float* out = (float*)d_out;
  float* zp = (float*)((char*)d_ws + WS_ZP_B);
  float* po = (float*)((char*)d_ws + WS_PO_B);

  prep_kernel<<<4384, 256, 0, stream>>>(q, k, v, pe, ws);
  attn_kernel<<<512, 256, 0, stream>>>(ws, cv, po, zp);
  norm_kernel<<<1024, 256, 0, stream>>>(zp, po, out);
}